// Round 1
// baseline (80.666 us; speedup 1.0000x reference)
//
#include <hip/hip_runtime.h>
#include <math.h>

#define NTH 256

__global__ __launch_bounds__(NTH) void iou_loss_kernel(
    const float* __restrict__ pred, const float* __restrict__ target,
    const float* __restrict__ weight, double* __restrict__ acc, int n)
{
    int i = blockIdx.x * blockDim.x + threadIdx.x;
    float loss = 0.0f;
    if (i < n) {
        float b1[7], b2[7];
        #pragma unroll
        for (int k = 0; k < 7; ++k) { b1[k] = pred[i*7+k]; b2[k] = target[i*7+k]; }

        // ---- box2corners (x,y,w,l,yaw) ----
        const float dxs[4] = {0.5f,-0.5f,-0.5f,0.5f};
        const float dys[4] = {0.5f,0.5f,-0.5f,-0.5f};
        float c1x[4], c1y[4], c2x[4], c2y[4];
        {
            float ca = cosf(b1[6]), sa = sinf(b1[6]);
            #pragma unroll
            for (int k = 0; k < 4; ++k) {
                float xs = dxs[k]*b1[3], ys = dys[k]*b1[4];
                c1x[k] = b1[0] + xs*ca - ys*sa;
                c1y[k] = b1[1] + xs*sa + ys*ca;
            }
            float cb = cosf(b2[6]), sb = sinf(b2[6]);
            #pragma unroll
            for (int k = 0; k < 4; ++k) {
                float xs = dxs[k]*b2[3], ys = dys[k]*b2[4];
                c2x[k] = b2[0] + xs*cb - ys*sb;
                c2y[k] = b2[1] + xs*sb + ys*cb;
            }
        }

        float vx[24], vy[24];
        unsigned vmask = 0;

        // verts 0-3 = c1 corners, 4-7 = c2 corners
        #pragma unroll
        for (int k = 0; k < 4; ++k) { vx[k]=c1x[k]; vy[k]=c1y[k]; vx[4+k]=c2x[k]; vy[4+k]=c2y[k]; }

        // ---- points_in_box: c1 corners in box2 (bits 0-3) ----
        {
            float ax=c2x[0], ay=c2y[0];
            float abx=c2x[1]-ax, aby=c2y[1]-ay;
            float adx=c2x[3]-ax, ady=c2y[3]-ay;
            float ab2=abx*abx+aby*aby, ad2=adx*adx+ady*ady;
            #pragma unroll
            for (int k = 0; k < 4; ++k) {
                float apx = c1x[k]-ax, apy = c1y[k]-ay;
                float pab = (apx*abx+apy*aby)/ab2;
                float pad = (apx*adx+apy*ady)/ad2;
                const float e = 1e-6f;
                if (pab > -e && pab < 1.0f+e && pad > -e && pad < 1.0f+e) vmask |= (1u<<k);
            }
        }
        // ---- c2 corners in box1 (bits 4-7) ----
        {
            float ax=c1x[0], ay=c1y[0];
            float abx=c1x[1]-ax, aby=c1y[1]-ay;
            float adx=c1x[3]-ax, ady=c1y[3]-ay;
            float ab2=abx*abx+aby*aby, ad2=adx*adx+ady*ady;
            #pragma unroll
            for (int k = 0; k < 4; ++k) {
                float apx = c2x[k]-ax, apy = c2y[k]-ay;
                float pab = (apx*abx+apy*aby)/ab2;
                float pad = (apx*adx+apy*ady)/ad2;
                const float e = 1e-6f;
                if (pab > -e && pab < 1.0f+e && pad > -e && pad < 1.0f+e) vmask |= (1u<<(4+k));
            }
        }

        // ---- edge-edge intersections (bits 8-23, index 8 + i*4 + j) ----
        #pragma unroll
        for (int ii = 0; ii < 4; ++ii) {
            float p1x=c1x[ii], p1y=c1y[ii];
            float d1x=c1x[(ii+1)&3]-p1x, d1y=c1y[(ii+1)&3]-p1y;
            #pragma unroll
            for (int jj = 0; jj < 4; ++jj) {
                float q1x=c2x[jj], q1y=c2y[jj];
                float d2x=c2x[(jj+1)&3]-q1x, d2y=c2y[(jj+1)&3]-q1y;
                float rx=q1x-p1x, ry=q1y-p1y;
                float denom = d1x*d2y - d1y*d2x;
                float safe = (fabsf(denom) < 1e-8f) ? 1.0f : denom;
                float t = (rx*d2y - ry*d2x)/safe;
                float u = (rx*d1y - ry*d1x)/safe;
                bool ok = (fabsf(denom) >= 1e-8f) && (t>0.0f) && (t<1.0f) && (u>0.0f) && (u<1.0f);
                int v = 8 + ii*4 + jj;
                vx[v] = ok ? p1x + t*d1x : 0.0f;
                vy[v] = ok ? p1y + t*d1y : 0.0f;
                if (ok) vmask |= (1u<<v);
            }
        }

        // ---- mean of valid verts ----
        int m = __popc(vmask & 0xFFFFFFu);
        float sx=0.0f, sy=0.0f;
        #pragma unroll
        for (int k=0;k<24;++k) {
            bool v = (vmask>>k)&1;
            sx += v ? vx[k] : 0.0f;
            sy += v ? vy[k] : 0.0f;
        }
        float mnum = (float)(m < 1 ? 1 : m);
        float mx = sx/mnum, my = sy/mnum;

        // ---- center + angles (invalid -> 1e8 exactly like reference) ----
        float ang[24];
        #pragma unroll
        for (int k=0;k<24;++k) {
            vx[k] -= mx; vy[k] -= my;
            ang[k] = ((vmask>>k)&1) ? atan2f(vy[k], vx[k]) : 1e8f;
        }

        // ---- stable ranks (reproduces stable argsort ordering) ----
        int rnk[24];
        #pragma unroll
        for (int k=0;k<24;++k) {
            int r=0;
            #pragma unroll
            for (int j=0;j<24;++j)
                r += (int)((ang[j] < ang[k]) || (ang[j]==ang[k] && j<k));
            rnk[k]=r;
        }

        // ---- shoelace over valid verts in angular order ----
        float area2 = 0.0f;
        #pragma unroll
        for (int k=0;k<24;++k) {
            bool vk = (vmask>>k)&1;
            int tr = rnk[k]+1; tr = (tr==m) ? 0 : tr;
            float sxx=0.0f, syy=0.0f;
            #pragma unroll
            for (int j=0;j<24;++j) {
                bool hit = (((vmask>>j)&1) != 0) && (rnk[j]==tr);
                sxx = hit ? vx[j] : sxx;
                syy = hit ? vy[j] : syy;
            }
            area2 += vk ? (vx[k]*syy - vy[k]*sxx) : 0.0f;
        }
        float area = 0.5f*fabsf(area2);
        if (m <= 2) area = 0.0f;

        // ---- z overlap + volumes + iou ----
        float zmax = fminf(b1[2]+0.5f*b1[5], b2[2]+0.5f*b2[5]);
        float zmin = fmaxf(b1[2]-0.5f*b1[5], b2[2]-0.5f*b2[5]);
        float dz = zmax - zmin; dz = dz < 0.0f ? 0.0f : dz;
        float inter_vol = area * dz;
        float v1 = b1[3]*b1[4]*b1[5];
        float v2 = b2[3]*b2[4]*b2[5];
        float iou = inter_vol / (v1 + v2 - inter_vol + 1e-8f);
        loss = (1.0f - iou) * weight[i];
    }

    // ---- block reduction -> double atomic ----
    #pragma unroll
    for (int off = 32; off > 0; off >>= 1) loss += __shfl_down(loss, off, 64);
    __shared__ float wsum[NTH/64];
    int lane = threadIdx.x & 63, wid = threadIdx.x >> 6;
    if (lane == 0) wsum[wid] = loss;
    __syncthreads();
    if (threadIdx.x == 0) {
        float s = 0.0f;
        #pragma unroll
        for (int w = 0; w < NTH/64; ++w) s += wsum[w];
        atomicAdd(acc, (double)s);
    }
}

__global__ void finalize_kernel(const double* __restrict__ acc, float* __restrict__ out, double inv_n) {
    out[0] = (float)(acc[0] * inv_n);
}

extern "C" void kernel_launch(void* const* d_in, const int* in_sizes, int n_in,
                              void* d_out, int out_size, void* d_ws, size_t ws_size,
                              hipStream_t stream) {
    const float* pred   = (const float*)d_in[0];
    const float* target = (const float*)d_in[1];
    const float* weight = (const float*)d_in[2];
    int n = in_sizes[2];
    double* acc = (double*)d_ws;
    hipMemsetAsync(d_ws, 0, sizeof(double), stream);
    int blocks = (n + NTH - 1) / NTH;
    hipLaunchKernelGGL(iou_loss_kernel, dim3(blocks), dim3(NTH), 0, stream,
                       pred, target, weight, acc, n);
    hipLaunchKernelGGL(finalize_kernel, dim3(1), dim3(1), 0, stream,
                       acc, (float*)d_out, 1.0 / (double)n);
}

// Round 2
// 42.956 us; speedup vs baseline: 1.8779x; 1.8779x over previous
//
#include <hip/hip_runtime.h>
#include <math.h>

#define NTH 256

// ---- constexpr Batcher odd-even mergesort network for 24 elements ----
struct Net { int a[256]; int b[256]; int n; };
static constexpr Net make_net() {
    Net t{}; t.n = 0;
    const int N = 24;
    for (int p = 1; p < N; p <<= 1)
        for (int k = p; k >= 1; k >>= 1)
            for (int j = k % p; j + k < N; j += 2 * k)
                for (int i = 0; i < k && i + j + k < N; ++i)
                    if ((i + j) / (2 * p) == (i + j + k) / (2 * p)) {
                        t.a[t.n] = i + j; t.b[t.n] = i + j + k; ++t.n;
                    }
    return t;
}
static constexpr Net NET = make_net();

__device__ __forceinline__ float frcp(float x) { return __builtin_amdgcn_rcpf(x); }

__global__ __launch_bounds__(NTH) void iou_loss_kernel(
    const float* __restrict__ pred, const float* __restrict__ target,
    const float* __restrict__ weight, double* __restrict__ acc, int n)
{
    int i = blockIdx.x * blockDim.x + threadIdx.x;
    float loss = 0.0f;
    if (i < n) {
        float b1[7], b2[7];
        #pragma unroll
        for (int k = 0; k < 7; ++k) { b1[k] = pred[i*7+k]; b2[k] = target[i*7+k]; }

        // z-overlap + volumes (free b arrays early)
        float zmax = fminf(b1[2]+0.5f*b1[5], b2[2]+0.5f*b2[5]);
        float zmin = fmaxf(b1[2]-0.5f*b1[5], b2[2]-0.5f*b2[5]);
        float dz = zmax - zmin; dz = dz < 0.0f ? 0.0f : dz;
        float v1 = b1[3]*b1[4]*b1[5];
        float v2 = b2[3]*b2[4]*b2[5];

        // ---- box2corners ----
        const float dxs[4] = {0.5f,-0.5f,-0.5f,0.5f};
        const float dys[4] = {0.5f,0.5f,-0.5f,-0.5f};
        float c1x[4], c1y[4], c2x[4], c2y[4];
        {
            float ca = __cosf(b1[6]), sa = __sinf(b1[6]);
            #pragma unroll
            for (int k = 0; k < 4; ++k) {
                float xs = dxs[k]*b1[3], ys = dys[k]*b1[4];
                c1x[k] = b1[0] + xs*ca - ys*sa;
                c1y[k] = b1[1] + xs*sa + ys*ca;
            }
            float cb = __cosf(b2[6]), sb = __sinf(b2[6]);
            #pragma unroll
            for (int k = 0; k < 4; ++k) {
                float xs = dxs[k]*b2[3], ys = dys[k]*b2[4];
                c2x[k] = b2[0] + xs*cb - ys*sb;
                c2y[k] = b2[1] + xs*sb + ys*cb;
            }
        }

        float vx[24], vy[24];
        unsigned vmask = 0;

        #pragma unroll
        for (int k = 0; k < 4; ++k) { vx[k]=c1x[k]; vy[k]=c1y[k]; vx[4+k]=c2x[k]; vy[4+k]=c2y[k]; }

        // ---- c1 corners in box2 (bits 0-3) ----
        {
            float ax=c2x[0], ay=c2y[0];
            float abx=c2x[1]-ax, aby=c2y[1]-ay;
            float adx=c2x[3]-ax, ady=c2y[3]-ay;
            float iab2 = frcp(abx*abx+aby*aby), iad2 = frcp(adx*adx+ady*ady);
            #pragma unroll
            for (int k = 0; k < 4; ++k) {
                float apx = c1x[k]-ax, apy = c1y[k]-ay;
                float pab = (apx*abx+apy*aby)*iab2;
                float pad = (apx*adx+apy*ady)*iad2;
                const float e = 1e-6f;
                if (pab > -e && pab < 1.0f+e && pad > -e && pad < 1.0f+e) vmask |= (1u<<k);
            }
        }
        // ---- c2 corners in box1 (bits 4-7) ----
        {
            float ax=c1x[0], ay=c1y[0];
            float abx=c1x[1]-ax, aby=c1y[1]-ay;
            float adx=c1x[3]-ax, ady=c1y[3]-ay;
            float iab2 = frcp(abx*abx+aby*aby), iad2 = frcp(adx*adx+ady*ady);
            #pragma unroll
            for (int k = 0; k < 4; ++k) {
                float apx = c2x[k]-ax, apy = c2y[k]-ay;
                float pab = (apx*abx+apy*aby)*iab2;
                float pad = (apx*adx+apy*ady)*iad2;
                const float e = 1e-6f;
                if (pab > -e && pab < 1.0f+e && pad > -e && pad < 1.0f+e) vmask |= (1u<<(4+k));
            }
        }

        // ---- edge-edge intersections (bits 8-23) ----
        #pragma unroll
        for (int ii = 0; ii < 4; ++ii) {
            float p1x=c1x[ii], p1y=c1y[ii];
            float d1x=c1x[(ii+1)&3]-p1x, d1y=c1y[(ii+1)&3]-p1y;
            #pragma unroll
            for (int jj = 0; jj < 4; ++jj) {
                float q1x=c2x[jj], q1y=c2y[jj];
                float d2x=c2x[(jj+1)&3]-q1x, d2y=c2y[(jj+1)&3]-q1y;
                float rx=q1x-p1x, ry=q1y-p1y;
                float denom = d1x*d2y - d1y*d2x;
                float safe = (fabsf(denom) < 1e-8f) ? 1.0f : denom;
                float inv = frcp(safe);
                float t = (rx*d2y - ry*d2x)*inv;
                float u = (rx*d1y - ry*d1x)*inv;
                bool ok = (fabsf(denom) >= 1e-8f) && (t>0.0f) && (t<1.0f) && (u>0.0f) && (u<1.0f);
                int v = 8 + ii*4 + jj;
                vx[v] = p1x + t*d1x;
                vy[v] = p1y + t*d1y;
                if (ok) vmask |= (1u<<v);
            }
        }

        // ---- mean of valid verts ----
        int m = __popc(vmask & 0xFFFFFFu);
        float sx=0.0f, sy=0.0f;
        #pragma unroll
        for (int k=0;k<24;++k) {
            bool v = (vmask>>k)&1;
            sx += v ? vx[k] : 0.0f;
            sy += v ? vy[k] : 0.0f;
        }
        float mnum = (float)(m < 1 ? 1 : m);
        float imn = frcp(mnum);
        float mx = sx*imn, my = sy*imn;

        // ---- center + pseudo-angle key (monotone in atan2; invalid -> 1e8) ----
        float key[24];
        #pragma unroll
        for (int k=0;k<24;++k) {
            float x = vx[k] - mx, y = vy[k] - my;
            vx[k] = x; vy[k] = y;
            float s = fabsf(x) + fabsf(y);
            float inv = (s == 0.0f) ? 0.0f : frcp(s);
            float r = x * inv;
            float pv = (y >= 0.0f) ? (1.0f - r) : (r - 1.0f);   // (-2,2], increasing with atan2
            key[k] = ((vmask>>k)&1) ? pv : 1e8f;
        }

        // ---- sorting network: sort (key, vx, vy) ascending by key ----
        #pragma unroll
        for (int s = 0; s < NET.n; ++s) {
            const int A = NET.a[s], B = NET.b[s];
            float ka = key[A], kb = key[B];
            float xa = vx[A],  xb = vx[B];
            float ya = vy[A],  yb = vy[B];
            bool sw = kb < ka;
            key[A] = sw ? kb : ka;  key[B] = sw ? ka : kb;
            vx[A]  = sw ? xb : xa;  vx[B]  = sw ? xa : xb;
            vy[A]  = sw ? yb : ya;  vy[B]  = sw ? ya : yb;
        }

        // ---- replace padding (k >= m) with first vertex, then cyclic shoelace ----
        float fx = vx[0], fy = vy[0];
        #pragma unroll
        for (int k = 0; k < 24; ++k) {
            bool pad = (k >= m);
            vx[k] = pad ? fx : vx[k];
            vy[k] = pad ? fy : vy[k];
        }
        float area2 = 0.0f;
        #pragma unroll
        for (int k = 0; k < 24; ++k) {
            int kn = (k == 23) ? 0 : k + 1;
            area2 += vx[k]*vy[kn] - vy[k]*vx[kn];
        }
        float area = 0.5f*fabsf(area2);
        area = (m > 2) ? area : 0.0f;

        // ---- iou ----
        float inter_vol = area * dz;
        float iou = inter_vol * frcp(v1 + v2 - inter_vol + 1e-8f);
        loss = (1.0f - iou) * weight[i];
    }

    // ---- block reduction -> double atomic ----
    #pragma unroll
    for (int off = 32; off > 0; off >>= 1) loss += __shfl_down(loss, off, 64);
    __shared__ float wsum[NTH/64];
    int lane = threadIdx.x & 63, wid = threadIdx.x >> 6;
    if (lane == 0) wsum[wid] = loss;
    __syncthreads();
    if (threadIdx.x == 0) {
        float s = 0.0f;
        #pragma unroll
        for (int w = 0; w < NTH/64; ++w) s += wsum[w];
        atomicAdd(acc, (double)s);
    }
}

__global__ void finalize_kernel(const double* __restrict__ acc, float* __restrict__ out, double inv_n) {
    out[0] = (float)(acc[0] * inv_n);
}

extern "C" void kernel_launch(void* const* d_in, const int* in_sizes, int n_in,
                              void* d_out, int out_size, void* d_ws, size_t ws_size,
                              hipStream_t stream) {
    const float* pred   = (const float*)d_in[0];
    const float* target = (const float*)d_in[1];
    const float* weight = (const float*)d_in[2];
    int n = in_sizes[2];
    double* acc = (double*)d_ws;
    hipMemsetAsync(d_ws, 0, sizeof(double), stream);
    int blocks = (n + NTH - 1) / NTH;
    hipLaunchKernelGGL(iou_loss_kernel, dim3(blocks), dim3(NTH), 0, stream,
                       pred, target, weight, acc, n);
    hipLaunchKernelGGL(finalize_kernel, dim3(1), dim3(1), 0, stream,
                       acc, (float*)d_out, 1.0 / (double)n);
}

// Round 3
// 37.445 us; speedup vs baseline: 2.1542x; 1.1472x over previous
//
#include <hip/hip_runtime.h>
#include <math.h>

#define NTH 256

__device__ __forceinline__ float frcp(float x) { return __builtin_amdgcn_rcpf(x); }

// Clip directed segment (ax,ay)->(bx,by) against the rotated rect centered at
// (ocx,ocy) with axis (c,s) and half-extents (heu,hev); return cross(A,B) of
// the clipped sub-segment (0 if empty). Sum over all 8 box edges = 2*Area(P∩Q).
__device__ __forceinline__ float clip_cross(
    float ax, float ay, float bx, float by,
    float ocx, float ocy, float c, float s,
    float heu, float hev)
{
    float dx = bx - ax, dy = by - ay;
    float rx = ax - ocx, ry = ay - ocy;
    float s0u = rx*c + ry*s,  sdu = dx*c + dy*s;
    float s0v = ry*c - rx*s,  sdv = dy*c - dx*s;
    float iu = frcp(sdu), iv = frcp(sdv);
    float ta = (-heu - s0u)*iu, tb = (heu - s0u)*iu;
    float tc = (-hev - s0v)*iv, td = (hev - s0v)*iv;
    float tlu = fminf(ta, tb), thu = fmaxf(ta, tb);
    float tlv = fminf(tc, td), thv = fmaxf(tc, td);
    float tin  = fmaxf(fmaxf(tlu, tlv), 0.0f);   // v_max3
    float tout = fminf(fminf(thu, thv), 1.0f);   // v_min3
    bool ok = tin < tout;
    float Ax = ax + tin*dx,  Ay = ay + tin*dy;
    float Bx = ax + tout*dx, By = ay + tout*dy;
    float cr = Ax*By - Ay*Bx;
    return ok ? cr : 0.0f;
}

__global__ __launch_bounds__(NTH) void iou_loss_kernel(
    const float* __restrict__ pred, const float* __restrict__ target,
    const float* __restrict__ weight, double* __restrict__ acc, int n)
{
    int i = blockIdx.x * blockDim.x + threadIdx.x;
    float loss = 0.0f;
    if (i < n) {
        float b1[7], b2[7];
        #pragma unroll
        for (int k = 0; k < 7; ++k) { b1[k] = pred[i*7+k]; b2[k] = target[i*7+k]; }

        // z-overlap + volumes
        float zmax = fminf(b1[2]+0.5f*b1[5], b2[2]+0.5f*b2[5]);
        float zmin = fmaxf(b1[2]-0.5f*b1[5], b2[2]-0.5f*b2[5]);
        float dz = fmaxf(zmax - zmin, 0.0f);
        float v1 = b1[3]*b1[4]*b1[5];
        float v2 = b2[3]*b2[4]*b2[5];

        // Work relative to box1 center (precision). Box2 center offset:
        float ox = b2[0] - b1[0], oy = b2[1] - b1[1];
        float ca1 = __cosf(b1[6]), sa1 = __sinf(b1[6]);
        float ca2 = __cosf(b2[6]), sa2 = __sinf(b2[6]);
        float hw1 = 0.5f*b1[3], hl1 = 0.5f*b1[4];
        float hw2 = 0.5f*b2[3], hl2 = 0.5f*b2[4];

        // Corners (CCW, same order as reference): offsets (±hw, ±hl) rotated.
        const float dxs[4] = {0.5f,-0.5f,-0.5f,0.5f};
        const float dys[4] = {0.5f,0.5f,-0.5f,-0.5f};
        float px[4], py[4], qx[4], qy[4];
        #pragma unroll
        for (int k = 0; k < 4; ++k) {
            float xs = dxs[k]*b1[3], ys = dys[k]*b1[4];
            px[k] = xs*ca1 - ys*sa1;
            py[k] = xs*sa1 + ys*ca1;
            float xs2 = dxs[k]*b2[3], ys2 = dys[k]*b2[4];
            qx[k] = ox + xs2*ca2 - ys2*sa2;
            qy[k] = oy + xs2*sa2 + ys2*ca2;
        }

        // Sum cross(A,B) over the directed boundary edges of P∩Q:
        // edges of P clipped to Q, plus edges of Q clipped to P.
        float s2 = 0.0f;
        #pragma unroll
        for (int k = 0; k < 4; ++k) {
            int kn = (k+1)&3;
            s2 += clip_cross(px[k],py[k], px[kn],py[kn], ox,oy, ca2,sa2, hw2,hl2);
            s2 += clip_cross(qx[k],qy[k], qx[kn],qy[kn], 0.0f,0.0f, ca1,sa1, hw1,hl1);
        }
        float area = 0.5f*fabsf(s2);

        float inter_vol = area * dz;
        float iou = inter_vol * frcp(v1 + v2 - inter_vol + 1e-8f);
        loss = (1.0f - iou) * weight[i];
    }

    // ---- block reduction -> double atomic ----
    #pragma unroll
    for (int off = 32; off > 0; off >>= 1) loss += __shfl_down(loss, off, 64);
    __shared__ float wsum[NTH/64];
    int lane = threadIdx.x & 63, wid = threadIdx.x >> 6;
    if (lane == 0) wsum[wid] = loss;
    __syncthreads();
    if (threadIdx.x == 0) {
        float sm = 0.0f;
        #pragma unroll
        for (int w = 0; w < NTH/64; ++w) sm += wsum[w];
        atomicAdd(acc, (double)sm);
    }
}

__global__ void finalize_kernel(const double* __restrict__ acc, float* __restrict__ out, double inv_n) {
    out[0] = (float)(acc[0] * inv_n);
}

extern "C" void kernel_launch(void* const* d_in, const int* in_sizes, int n_in,
                              void* d_out, int out_size, void* d_ws, size_t ws_size,
                              hipStream_t stream) {
    const float* pred   = (const float*)d_in[0];
    const float* target = (const float*)d_in[1];
    const float* weight = (const float*)d_in[2];
    int n = in_sizes[2];
    double* acc = (double*)d_ws;
    hipMemsetAsync(d_ws, 0, sizeof(double), stream);
    int blocks = (n + NTH - 1) / NTH;
    hipLaunchKernelGGL(iou_loss_kernel, dim3(blocks), dim3(NTH), 0, stream,
                       pred, target, weight, acc, n);
    hipLaunchKernelGGL(finalize_kernel, dim3(1), dim3(1), 0, stream,
                       acc, (float*)d_out, 1.0 / (double)n);
}

// Round 4
// 14.915 us; speedup vs baseline: 5.4084x; 2.5106x over previous
//
#include <hip/hip_runtime.h>
#include <math.h>

#define NTH 256

__device__ __forceinline__ float frcp(float x) { return __builtin_amdgcn_rcpf(x); }

__device__ __forceinline__ float get_comp(const float4& v, int c) {
    switch (c) { case 0: return v.x; case 1: return v.y; case 2: return v.z; default: return v.w; }
}

// Clip directed segment A->B against rotated rect (center (ocx,ocy), axis (c,s),
// half-extents heu,hev); return cross(A',B') of clipped sub-segment (0 if empty).
__device__ __forceinline__ float clip_cross(
    float ax, float ay, float bx, float by,
    float ocx, float ocy, float c, float s,
    float heu, float hev)
{
    float dx = bx - ax, dy = by - ay;
    float rx = ax - ocx, ry = ay - ocy;
    float s0u = rx*c + ry*s,  sdu = dx*c + dy*s;
    float s0v = ry*c - rx*s,  sdv = dy*c - dx*s;
    float iu = frcp(sdu), iv = frcp(sdv);
    float ta = (-heu - s0u)*iu, tb = (heu - s0u)*iu;
    float tc = (-hev - s0v)*iv, td = (hev - s0v)*iv;
    float tlu = fminf(ta, tb), thu = fmaxf(ta, tb);
    float tlv = fminf(tc, td), thv = fmaxf(tc, td);
    float tin  = fmaxf(fmaxf(tlu, tlv), 0.0f);
    float tout = fminf(fminf(thu, thv), 1.0f);
    bool ok = tin < tout;
    float Ax = ax + tin*dx,  Ay = ay + tin*dy;
    float Bx = ax + tout*dx, By = ay + tout*dy;
    float cr = Ax*By - Ay*Bx;
    return ok ? cr : 0.0f;
}

__device__ __forceinline__ float iou_loss_one(const float b1[7], const float b2[7], float w)
{
    float zmax = fminf(b1[2]+0.5f*b1[5], b2[2]+0.5f*b2[5]);
    float zmin = fmaxf(b1[2]-0.5f*b1[5], b2[2]-0.5f*b2[5]);
    float dz = fmaxf(zmax - zmin, 0.0f);
    float v1 = b1[3]*b1[4]*b1[5];
    float v2 = b2[3]*b2[4]*b2[5];

    float ox = b2[0] - b1[0], oy = b2[1] - b1[1];
    float ca1 = __cosf(b1[6]), sa1 = __sinf(b1[6]);
    float ca2 = __cosf(b2[6]), sa2 = __sinf(b2[6]);
    float hw1 = 0.5f*b1[3], hl1 = 0.5f*b1[4];
    float hw2 = 0.5f*b2[3], hl2 = 0.5f*b2[4];

    const float dxs[4] = {0.5f,-0.5f,-0.5f,0.5f};
    const float dys[4] = {0.5f,0.5f,-0.5f,-0.5f};
    float px[4], py[4], qx[4], qy[4];
    #pragma unroll
    for (int k = 0; k < 4; ++k) {
        float xs = dxs[k]*b1[3], ys = dys[k]*b1[4];
        px[k] = xs*ca1 - ys*sa1;
        py[k] = xs*sa1 + ys*ca1;
        float xs2 = dxs[k]*b2[3], ys2 = dys[k]*b2[4];
        qx[k] = ox + xs2*ca2 - ys2*sa2;
        qy[k] = oy + xs2*sa2 + ys2*ca2;
    }

    float s2 = 0.0f;
    #pragma unroll
    for (int k = 0; k < 4; ++k) {
        int kn = (k+1)&3;
        s2 += clip_cross(px[k],py[k], px[kn],py[kn], ox,oy, ca2,sa2, hw2,hl2);
        s2 += clip_cross(qx[k],qy[k], qx[kn],qy[kn], 0.0f,0.0f, ca1,sa1, hw1,hl1);
    }
    float area = 0.5f*fabsf(s2);

    float inter_vol = area * dz;
    float iou = inter_vol * frcp(v1 + v2 - inter_vol + 1e-8f);
    return (1.0f - iou) * w;
}

__global__ __launch_bounds__(NTH) void iou_loss_kernel(
    const float* __restrict__ pred, const float* __restrict__ target,
    const float* __restrict__ weight, float* __restrict__ partial, int n)
{
    int t = blockIdx.x * blockDim.x + threadIdx.x;
    int i4 = t * 4;
    float loss = 0.0f;
    if (i4 + 3 < n) {
        // 4 rows = 28 floats = 7 x float4, base 112B-aligned.
        float4 p[7], q[7];
        const float4* pp = reinterpret_cast<const float4*>(pred + i4*7);
        const float4* qq = reinterpret_cast<const float4*>(target + i4*7);
        #pragma unroll
        for (int k = 0; k < 7; ++k) { p[k] = pp[k]; q[k] = qq[k]; }
        float4 wv = *reinterpret_cast<const float4*>(weight + i4);

        #pragma unroll
        for (int r = 0; r < 4; ++r) {
            float b1[7], b2[7];
            #pragma unroll
            for (int j = 0; j < 7; ++j) {
                int f = r*7 + j;
                b1[j] = get_comp(p[f >> 2], f & 3);
                b2[j] = get_comp(q[f >> 2], f & 3);
            }
            float w = get_comp(wv, r);
            loss += iou_loss_one(b1, b2, w);
        }
    } else {
        for (int r = 0; r < 4; ++r) {
            int i = i4 + r;
            if (i < n) {
                float b1[7], b2[7];
                #pragma unroll
                for (int j = 0; j < 7; ++j) { b1[j] = pred[i*7+j]; b2[j] = target[i*7+j]; }
                loss += iou_loss_one(b1, b2, weight[i]);
            }
        }
    }

    // block reduction -> per-block partial (no atomics)
    #pragma unroll
    for (int off = 32; off > 0; off >>= 1) loss += __shfl_down(loss, off, 64);
    __shared__ float wsum[NTH/64];
    int lane = threadIdx.x & 63, wid = threadIdx.x >> 6;
    if (lane == 0) wsum[wid] = loss;
    __syncthreads();
    if (threadIdx.x == 0) {
        float s = 0.0f;
        #pragma unroll
        for (int w = 0; w < NTH/64; ++w) s += wsum[w];
        partial[blockIdx.x] = s;
    }
}

__global__ __launch_bounds__(NTH) void reduce_kernel(
    const float* __restrict__ partial, int nb, float* __restrict__ out, double inv_n)
{
    double s = 0.0;
    for (int j = threadIdx.x; j < nb; j += NTH) s += (double)partial[j];
    #pragma unroll
    for (int off = 32; off > 0; off >>= 1) s += __shfl_down(s, off, 64);
    __shared__ double wsum[NTH/64];
    int lane = threadIdx.x & 63, wid = threadIdx.x >> 6;
    if (lane == 0) wsum[wid] = s;
    __syncthreads();
    if (threadIdx.x == 0) {
        double tot = 0.0;
        #pragma unroll
        for (int w = 0; w < NTH/64; ++w) tot += wsum[w];
        out[0] = (float)(tot * inv_n);
    }
}

extern "C" void kernel_launch(void* const* d_in, const int* in_sizes, int n_in,
                              void* d_out, int out_size, void* d_ws, size_t ws_size,
                              hipStream_t stream) {
    const float* pred   = (const float*)d_in[0];
    const float* target = (const float*)d_in[1];
    const float* weight = (const float*)d_in[2];
    int n = in_sizes[2];
    float* partial = (float*)d_ws;
    int nt = (n + 3) / 4;
    int nblocks = (nt + NTH - 1) / NTH;
    hipLaunchKernelGGL(iou_loss_kernel, dim3(nblocks), dim3(NTH), 0, stream,
                       pred, target, weight, partial, n);
    hipLaunchKernelGGL(reduce_kernel, dim3(1), dim3(NTH), 0, stream,
                       partial, nblocks, (float*)d_out, 1.0 / (double)n);
}